// Round 3
// baseline (425.025 us; speedup 1.0000x reference)
//
#include <hip/hip_runtime.h>
#include <math.h>

// N=100000, E=500000, D=256.
// Factored: concat(h[s],h[d])@W1 == h[s]@W1[0:256] + h[d]@W1[256:512]
//   Phase 1 (GEMM): PQ[n,0:256]=h[n]@W1_top ; PQ[n,256:512]=h[n]@W1_bot
//   Phase 2: per edge sigmoid( relu(PQ[s,0:256]+PQ[d,256:512]+b1) . W2 + b2 )
// Float dtype (bf16 vs fp32) is UNKNOWN (test metadata conflicts with the
// reference source), so a probe kernel detects it from h's bit patterns and
// every kernel is templated on MODE (1=bf16, 0=fp32) with early-exit.

typedef __attribute__((ext_vector_type(8))) short short8;
typedef __attribute__((ext_vector_type(4))) float floatx4;

#define D_FEAT 256

__device__ __forceinline__ float bf2f(unsigned short u) {
    union { unsigned u32; float f; } v; v.u32 = ((unsigned)u) << 16; return v.f;
}
__device__ __forceinline__ unsigned short f2bf(float f) {
    union { float f; unsigned u32; } v; v.f = f;
    unsigned x = v.u32;
    return (unsigned short)((x + 0x7fffu + ((x >> 16) & 1u)) >> 16);
}
__device__ __forceinline__ float sigmoid_safe(float r) {
    r = fminf(fmaxf(r, -30.f), 30.f);
    return 1.f / (1.f + expf(-r));
}

// ---- dtype probe: bf16 N(0,1) shorts have exp field in [100,140] ~100% of
// the time; fp32 reinterpreted as shorts only ~58%. Threshold 90%.
__global__ __launch_bounds__(256) void probe_dtype(const unsigned short* __restrict__ h,
                                                   int* __restrict__ flag) {
    __shared__ int cnt[256];
    const int t = threadIdx.x;
    int c = 0;
    #pragma unroll
    for (int i = 0; i < 8; ++i) {
        unsigned e = (h[t * 8 + i] >> 7) & 0xFF;
        c += (e >= 100 && e <= 140) ? 1 : 0;
    }
    cnt[t] = c;
    __syncthreads();
    if (t == 0) {
        int s = 0;
        for (int i = 0; i < 256; ++i) s += cnt[i];
        flag[0] = (s >= 1843) ? 1 : 0;   // 1 = bf16, 0 = fp32
    }
}

// Wt[j][k] bf16 [512,256]: j<256 -> W1[k][j]; j>=256 -> W1[256+k][j-256]
template <int MODE>
__global__ __launch_bounds__(256) void build_wt_t(const void* __restrict__ W1v,
                                                  unsigned short* __restrict__ Wt,
                                                  const int* __restrict__ flag) {
    if (flag[0] != MODE) return;
    int j = blockIdx.x, k = threadIdx.x;
    size_t idx = (j < 256) ? ((size_t)k * 256 + j) : ((size_t)(k + 256) * 256 + (j - 256));
    unsigned short v;
    if constexpr (MODE == 1) v = ((const unsigned short*)W1v)[idx];
    else                     v = f2bf(((const float*)W1v)[idx]);
    Wt[(size_t)j * 256 + k] = v;
}

// PQ[N,512] = h[N,256] @ W'[256,512] (Wt = W'^T, bf16). Tile 64x64, BK=32.
template <int MODE>
__global__ __launch_bounds__(256) void gemm_pq_t(const void* __restrict__ hv,
                                                 const unsigned short* __restrict__ Wt,
                                                 unsigned short* __restrict__ PQ,
                                                 int N, const int* __restrict__ flag) {
    if (flag[0] != MODE) return;
    __shared__ unsigned short As[64][40];
    __shared__ unsigned short Bs[64][40];

    const int tid  = threadIdx.x;
    const int wid  = tid >> 6;
    const int lane = tid & 63;
    const int wr   = wid >> 1;
    const int wc   = wid & 1;
    const int quad = lane >> 4;
    const int l16  = lane & 15;

    const int m_base = blockIdx.x * 64;
    const int n_base = blockIdx.y * 64;

    floatx4 acc[2][2] = {};

    const int sm = tid >> 2;
    const int sk = (tid & 3) * 8;

    for (int k0 = 0; k0 < D_FEAT; k0 += 32) {
        int gm = m_base + sm;
        short8 av = {};
        if (gm < N) {
            if constexpr (MODE == 1) {
                av = *(const short8*)((const unsigned short*)hv + (size_t)gm * D_FEAT + k0 + sk);
            } else {
                const float* p = (const float*)hv + (size_t)gm * D_FEAT + k0 + sk;
                floatx4 f0 = *(const floatx4*)p;
                floatx4 f1 = *(const floatx4*)(p + 4);
                av[0] = (short)f2bf(f0.x); av[1] = (short)f2bf(f0.y);
                av[2] = (short)f2bf(f0.z); av[3] = (short)f2bf(f0.w);
                av[4] = (short)f2bf(f1.x); av[5] = (short)f2bf(f1.y);
                av[6] = (short)f2bf(f1.z); av[7] = (short)f2bf(f1.w);
            }
        }
        *(short8*)(&As[sm][sk]) = av;
        short8 bv = *(const short8*)(Wt + (size_t)(n_base + sm) * D_FEAT + k0 + sk);
        *(short8*)(&Bs[sm][sk]) = bv;
        __syncthreads();

        short8 af0 = *(const short8*)(&As[wr * 32 + l16][quad * 8]);
        short8 af1 = *(const short8*)(&As[wr * 32 + 16 + l16][quad * 8]);
        short8 bf0 = *(const short8*)(&Bs[wc * 32 + l16][quad * 8]);
        short8 bf1 = *(const short8*)(&Bs[wc * 32 + 16 + l16][quad * 8]);

        acc[0][0] = __builtin_amdgcn_mfma_f32_16x16x32_bf16(af0, bf0, acc[0][0], 0, 0, 0);
        acc[0][1] = __builtin_amdgcn_mfma_f32_16x16x32_bf16(af0, bf1, acc[0][1], 0, 0, 0);
        acc[1][0] = __builtin_amdgcn_mfma_f32_16x16x32_bf16(af1, bf0, acc[1][0], 0, 0, 0);
        acc[1][1] = __builtin_amdgcn_mfma_f32_16x16x32_bf16(af1, bf1, acc[1][1], 0, 0, 0);
        __syncthreads();
    }

    #pragma unroll
    for (int i = 0; i < 2; ++i)
        #pragma unroll
        for (int j = 0; j < 2; ++j)
            #pragma unroll
            for (int r = 0; r < 4; ++r) {
                int row = m_base + wr * 32 + i * 16 + quad * 4 + r;
                int col = n_base + wc * 32 + j * 16 + l16;
                if (row < N) PQ[(size_t)row * 512 + col] = f2bf(acc[i][j][r]);
            }
}

// One wave per edge; lane covers 4 consecutive features. PQ always bf16.
template <int MODE>
__global__ __launch_bounds__(256) void edge_score_t(const unsigned short* __restrict__ PQ,
                                                    const int* __restrict__ src,
                                                    const int* __restrict__ dst,
                                                    const void* __restrict__ b1v,
                                                    const void* __restrict__ W2v,
                                                    const void* __restrict__ b2v,
                                                    void* __restrict__ outv,
                                                    int E, const int* __restrict__ flag) {
    if (flag[0] != MODE) return;
    const int wave = threadIdx.x >> 6;
    const int lane = threadIdx.x & 63;
    const int e = blockIdx.x * 4 + wave;
    if (e >= E) return;

    const int s = src[e];
    const int d = dst[e];

    const ushort4 p = *(const ushort4*)(PQ + (size_t)s * 512 + lane * 4);
    const ushort4 q = *(const ushort4*)(PQ + (size_t)d * 512 + 256 + lane * 4);

    float b0, b1f_, b2f_, b3, w0, w1, w2, w3, bias2;
    if constexpr (MODE == 1) {
        const ushort4 bv = *(const ushort4*)((const unsigned short*)b1v + lane * 4);
        const ushort4 wv = *(const ushort4*)((const unsigned short*)W2v + lane * 4);
        b0 = bf2f(bv.x); b1f_ = bf2f(bv.y); b2f_ = bf2f(bv.z); b3 = bf2f(bv.w);
        w0 = bf2f(wv.x); w1 = bf2f(wv.y); w2 = bf2f(wv.z); w3 = bf2f(wv.w);
        bias2 = bf2f(((const unsigned short*)b2v)[0]);
    } else {
        floatx4 bv = *(const floatx4*)((const float*)b1v + lane * 4);
        floatx4 wv = *(const floatx4*)((const float*)W2v + lane * 4);
        b0 = bv.x; b1f_ = bv.y; b2f_ = bv.z; b3 = bv.w;
        w0 = wv.x; w1 = wv.y; w2 = wv.z; w3 = wv.w;
        bias2 = ((const float*)b2v)[0];
    }

    float v0 = bf2f(p.x) + bf2f(q.x) + b0;
    float v1 = bf2f(p.y) + bf2f(q.y) + b1f_;
    float v2 = bf2f(p.z) + bf2f(q.z) + b2f_;
    float v3 = bf2f(p.w) + bf2f(q.w) + b3;
    v0 = v0 > 0.f ? v0 : 0.f;
    v1 = v1 > 0.f ? v1 : 0.f;
    v2 = v2 > 0.f ? v2 : 0.f;
    v3 = v3 > 0.f ? v3 : 0.f;
    float sum = v0 * w0 + v1 * w1 + v2 * w2 + v3 * w3;

    #pragma unroll
    for (int off = 32; off > 0; off >>= 1)
        sum += __shfl_xor(sum, off);

    if (lane == 0) {
        float r = sigmoid_safe(sum + bias2);
        if constexpr (MODE == 1) ((unsigned short*)outv)[e] = f2bf(r);
        else                     ((float*)outv)[e] = r;
    }
}

// Zero-workspace fallback: one block per edge. flag==nullptr => assume MODE.
template <int MODE>
__global__ __launch_bounds__(256) void edge_fused_t(const void* __restrict__ hv,
                                                    const int* __restrict__ src,
                                                    const int* __restrict__ dst,
                                                    const void* __restrict__ W1v,
                                                    const void* __restrict__ b1v,
                                                    const void* __restrict__ W2v,
                                                    const void* __restrict__ b2v,
                                                    void* __restrict__ outv,
                                                    int E, const int* __restrict__ flag) {
    if (flag && flag[0] != MODE) return;
    __shared__ float he[512];
    __shared__ float wsum[4];
    const int e = blockIdx.x;
    if (e >= E) return;
    const int t = threadIdx.x;
    const int s = src[e];
    const int d = dst[e];

    if constexpr (MODE == 1) {
        he[t]       = bf2f(((const unsigned short*)hv)[(size_t)s * 256 + t]);
        he[256 + t] = bf2f(((const unsigned short*)hv)[(size_t)d * 256 + t]);
    } else {
        he[t]       = ((const float*)hv)[(size_t)s * 256 + t];
        he[256 + t] = ((const float*)hv)[(size_t)d * 256 + t];
    }
    __syncthreads();

    float acc;
    if constexpr (MODE == 1) acc = bf2f(((const unsigned short*)b1v)[t]);
    else                     acc = ((const float*)b1v)[t];

    #pragma unroll 8
    for (int k = 0; k < 512; ++k) {
        float w;
        if constexpr (MODE == 1) w = bf2f(((const unsigned short*)W1v)[(size_t)k * 256 + t]);
        else                     w = ((const float*)W1v)[(size_t)k * 256 + t];
        acc += he[k] * w;
    }

    float w2;
    if constexpr (MODE == 1) w2 = bf2f(((const unsigned short*)W2v)[t]);
    else                     w2 = ((const float*)W2v)[t];
    acc = fmaxf(acc, 0.f) * w2;

    #pragma unroll
    for (int off = 32; off > 0; off >>= 1)
        acc += __shfl_xor(acc, off);
    if ((t & 63) == 0) wsum[t >> 6] = acc;
    __syncthreads();

    if (t == 0) {
        float bias2;
        if constexpr (MODE == 1) bias2 = bf2f(((const unsigned short*)b2v)[0]);
        else                     bias2 = ((const float*)b2v)[0];
        float r = sigmoid_safe(wsum[0] + wsum[1] + wsum[2] + wsum[3] + bias2);
        if constexpr (MODE == 1) ((unsigned short*)outv)[e] = f2bf(r);
        else                     ((float*)outv)[e] = r;
    }
}

extern "C" void kernel_launch(void* const* d_in, const int* in_sizes, int n_in,
                              void* d_out, int out_size, void* d_ws, size_t ws_size,
                              hipStream_t stream) {
    const void* h  = d_in[0];
    const int* src = (const int*)d_in[1];
    const int* dst = (const int*)d_in[2];
    const void* W1 = d_in[3];
    const void* b1 = d_in[4];
    const void* W2 = d_in[5];
    const void* b2 = d_in[6];

    const int N = in_sizes[0] / D_FEAT;   // 100000
    const int E = in_sizes[1];            // 500000

    const size_t FLAG_BYTES = 256;
    const size_t wt_elems = (size_t)512 * D_FEAT;
    const size_t pq_elems = (size_t)N * 512;
    const size_t need = FLAG_BYTES + (wt_elems + pq_elems) * sizeof(unsigned short);

    int* flag = (int*)d_ws;
    unsigned short* Wt = (unsigned short*)((char*)d_ws + FLAG_BYTES);
    unsigned short* PQ = Wt + wt_elems;

    if (ws_size >= need) {
        probe_dtype<<<1, 256, 0, stream>>>((const unsigned short*)h, flag);

        build_wt_t<1><<<512, 256, 0, stream>>>(W1, Wt, flag);
        build_wt_t<0><<<512, 256, 0, stream>>>(W1, Wt, flag);

        dim3 ggrid((N + 63) / 64, 512 / 64);
        gemm_pq_t<1><<<ggrid, 256, 0, stream>>>(h, Wt, PQ, N, flag);
        gemm_pq_t<0><<<ggrid, 256, 0, stream>>>(h, Wt, PQ, N, flag);

        int egrid = (E + 3) / 4;
        edge_score_t<1><<<egrid, 256, 0, stream>>>(PQ, src, dst, b1, W2, b2, d_out, E, flag);
        edge_score_t<0><<<egrid, 256, 0, stream>>>(PQ, src, dst, b1, W2, b2, d_out, E, flag);
    } else if (ws_size >= FLAG_BYTES) {
        probe_dtype<<<1, 256, 0, stream>>>((const unsigned short*)h, flag);
        edge_fused_t<1><<<E, 256, 0, stream>>>(h, src, dst, W1, b1, W2, b2, d_out, E, flag);
        edge_fused_t<0><<<E, 256, 0, stream>>>(h, src, dst, W1, b1, W2, b2, d_out, E, flag);
    } else {
        edge_fused_t<1><<<E, 256, 0, stream>>>(h, src, dst, W1, b1, W2, b2, d_out, E, nullptr);
    }
}

// Round 5
// 304.769 us; speedup vs baseline: 1.3946x; 1.3946x over previous
//
#include <hip/hip_runtime.h>
#include <math.h>

// N=100000, E=500000, D=256.
// Factored: concat(h[s],h[d])@W1 == h[s]@W1[0:256] + h[d]@W1[256:512]
//   Phase 1 (GEMM): PQ[n,0:256]=h[n]@W1_top ; PQ[n,256:512]=h[n]@W1_bot
//     Grid over M only; A-tile (64x256, full K) LDS-resident; 16 n-chunks of
//     Wt (32x256 each) streamed through LDS (Wt 262 KB -> L2-hot). h read ONCE.
//   Phase 2: per edge sigmoid( relu(PQ[s,0:256]+PQ[d,256:512]+b1) . W2 + b2 )
//     Half-wave split: lanes 0-31 read P[src], lanes 32-63 read Q[dst] (16 B
//     per lane), paired via shfl_xor 32; 8 edges per wave.
// Scaffolding (probe + flag-guarded templates + FLAG_BYTES offset) kept
// verbatim from the passing R3 source — stripped variants failed twice with
// an identical environment-determined NaN signature.

typedef __attribute__((ext_vector_type(8))) short short8;
typedef __attribute__((ext_vector_type(4))) float floatx4;

#define D_FEAT 256
#define EPW 8

__device__ __forceinline__ float bf2f(unsigned short u) {
    union { unsigned u32; float f; } v; v.u32 = ((unsigned)u) << 16; return v.f;
}
__device__ __forceinline__ float lo16(unsigned u) {
    union { unsigned u32; float f; } v; v.u32 = u << 16; return v.f;
}
__device__ __forceinline__ float hi16(unsigned u) {
    union { unsigned u32; float f; } v; v.u32 = u & 0xffff0000u; return v.f;
}
__device__ __forceinline__ unsigned short f2bf(float f) {
    union { float f; unsigned u32; } v; v.f = f;
    unsigned x = v.u32;
    return (unsigned short)((x + 0x7fffu + ((x >> 16) & 1u)) >> 16);
}
__device__ __forceinline__ float sigmoid_safe(float r) {
    r = fminf(fmaxf(r, -30.f), 30.f);
    return 1.f / (1.f + expf(-r));
}

// ---- dtype probe: bf16 N(0,1) shorts have exp field in [100,140] ~100% of
// the time; fp32 reinterpreted as shorts only ~58%. Threshold 90%.
__global__ __launch_bounds__(256) void probe_dtype(const unsigned short* __restrict__ h,
                                                   int* __restrict__ flag) {
    __shared__ int cnt[256];
    const int t = threadIdx.x;
    int c = 0;
    #pragma unroll
    for (int i = 0; i < 8; ++i) {
        unsigned e = (h[t * 8 + i] >> 7) & 0xFF;
        c += (e >= 100 && e <= 140) ? 1 : 0;
    }
    cnt[t] = c;
    __syncthreads();
    if (t == 0) {
        int s = 0;
        for (int i = 0; i < 256; ++i) s += cnt[i];
        flag[0] = (s >= 1843) ? 1 : 0;   // 1 = bf16, 0 = fp32
    }
}

// Wt[j][k] bf16 [512,256]: j<256 -> W1[k][j]; j>=256 -> W1[256+k][j-256]
template <int MODE>
__global__ __launch_bounds__(256) void build_wt_t(const void* __restrict__ W1v,
                                                  unsigned short* __restrict__ Wt,
                                                  const int* __restrict__ flag) {
    if (flag[0] != MODE) return;
    int j = blockIdx.x, k = threadIdx.x;
    size_t idx = (j < 256) ? ((size_t)k * 256 + j) : ((size_t)(k + 256) * 256 + (j - 256));
    unsigned short v;
    if constexpr (MODE == 1) v = ((const unsigned short*)W1v)[idx];
    else                     v = f2bf(((const float*)W1v)[idx]);
    Wt[(size_t)j * 256 + k] = v;
}

// PQ[N,512] = h[N,256] @ W'[256,512] (Wt = W'^T, bf16).
// BM=64 with full K=256 A-tile resident; 16 n-chunks of 32 Wt rows.
// LDS: 64*264*2 + 32*264*2 = 50,688 B.
template <int MODE>
__global__ __launch_bounds__(256) void gemm_pq_t(const void* __restrict__ hv,
                                                 const unsigned short* __restrict__ Wt,
                                                 unsigned short* __restrict__ PQ,
                                                 int N, const int* __restrict__ flag) {
    if (flag[0] != MODE) return;
    __shared__ unsigned short As[64][264];   // +8 pad: 4-bank shift/row, 16B-aligned
    __shared__ unsigned short Bs[32][264];

    const int tid  = threadIdx.x;
    const int lane = tid & 63;
    const int wid  = tid >> 6;
    const int wr   = wid >> 1;      // m half (32 rows)
    const int wc   = wid & 1;       // n half (16 cols of the 32-col chunk)
    const int quad = lane >> 4;
    const int l16  = lane & 15;
    const int m_base = blockIdx.x * 64;

    const int srow = tid >> 5;          // 0..7
    const int scol = (tid & 31) * 8;    // 16 B per lane, 512 B per row

    // Stage full A tile (64 x 256) once — h read exactly once from HBM.
    #pragma unroll
    for (int i = 0; i < 8; ++i) {
        int r = i * 8 + srow;
        int gm = m_base + r;
        short8 v = {};
        if (gm < N) {
            if constexpr (MODE == 1) {
                v = *(const short8*)((const unsigned short*)hv + (size_t)gm * D_FEAT + scol);
            } else {
                const float* p = (const float*)hv + (size_t)gm * D_FEAT + scol;
                floatx4 f0 = *(const floatx4*)p;
                floatx4 f1 = *(const floatx4*)(p + 4);
                v[0] = (short)f2bf(f0.x); v[1] = (short)f2bf(f0.y);
                v[2] = (short)f2bf(f0.z); v[3] = (short)f2bf(f0.w);
                v[4] = (short)f2bf(f1.x); v[5] = (short)f2bf(f1.y);
                v[6] = (short)f2bf(f1.z); v[7] = (short)f2bf(f1.w);
            }
        }
        *(short8*)(&As[r][scol]) = v;
    }

    for (int nc = 0; nc < 16; ++nc) {
        #pragma unroll
        for (int i = 0; i < 4; ++i) {
            int r = i * 8 + srow;   // 0..31
            short8 v = *(const short8*)(Wt + (size_t)(nc * 32 + r) * D_FEAT + scol);
            *(short8*)(&Bs[r][scol]) = v;
        }
        __syncthreads();

        floatx4 acc[2] = {};
        #pragma unroll
        for (int kk = 0; kk < 8; ++kk) {
            const int k = kk * 32 + quad * 8;
            short8 a0 = *(const short8*)(&As[wr * 32 + l16][k]);
            short8 a1 = *(const short8*)(&As[wr * 32 + 16 + l16][k]);
            short8 b  = *(const short8*)(&Bs[wc * 16 + l16][k]);
            // Swapped operands: D row (quad*4+reg) <-> Wt's n, D col (l16) <-> h's m.
            acc[0] = __builtin_amdgcn_mfma_f32_16x16x32_bf16(b, a0, acc[0], 0, 0, 0);
            acc[1] = __builtin_amdgcn_mfma_f32_16x16x32_bf16(b, a1, acc[1], 0, 0, 0);
        }
        __syncthreads();   // all waves done reading Bs before restage

        #pragma unroll
        for (int i = 0; i < 2; ++i) {
            int m = m_base + wr * 32 + i * 16 + l16;
            if (m < N) {
                int n = nc * 32 + wc * 16 + quad * 4;
                ushort4 o;
                o.x = f2bf(acc[i][0]); o.y = f2bf(acc[i][1]);
                o.z = f2bf(acc[i][2]); o.w = f2bf(acc[i][3]);
                *(ushort4*)(PQ + (size_t)m * 512 + n) = o;
            }
        }
    }
}

// 8 edges per wave. Lane L<32 reads P[src] cols L*8..+7; lane L>=32 reads
// Q[dst] cols (PQ col = L*8 either way). shfl_xor 32 pairs P/Q; both halves
// then hold identical partials, butterfly 1..16 completes the 256-feature dot.
template <int MODE>
__global__ __launch_bounds__(256) void edge_score_t(const unsigned short* __restrict__ PQ,
                                                    const int* __restrict__ src,
                                                    const int* __restrict__ dst,
                                                    const void* __restrict__ b1v,
                                                    const void* __restrict__ W2v,
                                                    const void* __restrict__ b2v,
                                                    void* __restrict__ outv,
                                                    int E, const int* __restrict__ flag) {
    if (flag[0] != MODE) return;
    const int wave = threadIdx.x >> 6;
    const int lane = threadIdx.x & 63;
    const int e0 = (blockIdx.x * 4 + wave) * EPW;
    if (e0 >= E) return;
    const int l32 = lane & 31;
    const int* __restrict__ idxp = (lane >= 32) ? dst : src;

    float bf[8], wf[8];
    if constexpr (MODE == 1) {
        const uint4 bvr = *(const uint4*)((const unsigned short*)b1v + l32 * 8);
        const uint4 wvr = *(const uint4*)((const unsigned short*)W2v + l32 * 8);
        bf[0] = lo16(bvr.x); bf[1] = hi16(bvr.x); bf[2] = lo16(bvr.y); bf[3] = hi16(bvr.y);
        bf[4] = lo16(bvr.z); bf[5] = hi16(bvr.z); bf[6] = lo16(bvr.w); bf[7] = hi16(bvr.w);
        wf[0] = lo16(wvr.x); wf[1] = hi16(wvr.x); wf[2] = lo16(wvr.y); wf[3] = hi16(wvr.y);
        wf[4] = lo16(wvr.z); wf[5] = hi16(wvr.z); wf[6] = lo16(wvr.w); wf[7] = hi16(wvr.w);
    } else {
        const float* bp = (const float*)b1v + l32 * 8;
        const float* wp = (const float*)W2v + l32 * 8;
        #pragma unroll
        for (int t = 0; t < 8; ++t) { bf[t] = bp[t]; wf[t] = wp[t]; }
    }

    int node[EPW];
    #pragma unroll
    for (int i = 0; i < EPW; ++i) {
        int e = e0 + i; if (e >= E) e = E - 1;
        node[i] = idxp[e];
    }
    uint4 raw[EPW];   // 8 x 16 B gathers in flight per lane
    #pragma unroll
    for (int i = 0; i < EPW; ++i)
        raw[i] = *(const uint4*)(PQ + (size_t)node[i] * 512 + lane * 8);

    float res[EPW];
    #pragma unroll
    for (int i = 0; i < EPW; ++i) {
        uint4 o;
        o.x = (unsigned)__shfl_xor((int)raw[i].x, 32);
        o.y = (unsigned)__shfl_xor((int)raw[i].y, 32);
        o.z = (unsigned)__shfl_xor((int)raw[i].z, 32);
        o.w = (unsigned)__shfl_xor((int)raw[i].w, 32);
        float v0 = fmaxf(lo16(raw[i].x) + lo16(o.x) + bf[0], 0.f);
        float v1 = fmaxf(hi16(raw[i].x) + hi16(o.x) + bf[1], 0.f);
        float v2 = fmaxf(lo16(raw[i].y) + lo16(o.y) + bf[2], 0.f);
        float v3 = fmaxf(hi16(raw[i].y) + hi16(o.y) + bf[3], 0.f);
        float v4 = fmaxf(lo16(raw[i].z) + lo16(o.z) + bf[4], 0.f);
        float v5 = fmaxf(hi16(raw[i].z) + hi16(o.z) + bf[5], 0.f);
        float v6 = fmaxf(lo16(raw[i].w) + lo16(o.w) + bf[6], 0.f);
        float v7 = fmaxf(hi16(raw[i].w) + hi16(o.w) + bf[7], 0.f);
        float sum = v0 * wf[0] + v1 * wf[1] + v2 * wf[2] + v3 * wf[3]
                  + v4 * wf[4] + v5 * wf[5] + v6 * wf[6] + v7 * wf[7];
        #pragma unroll
        for (int off = 1; off <= 16; off <<= 1)
            sum += __shfl_xor(sum, off);
        res[i] = sum;
    }

    if (lane == 0) {
        float bias2;
        if constexpr (MODE == 1) bias2 = bf2f(((const unsigned short*)b2v)[0]);
        else                     bias2 = ((const float*)b2v)[0];
        if constexpr (MODE == 1) {
            union { short8 v; unsigned short u[8]; } r;
            #pragma unroll
            for (int i = 0; i < EPW; ++i)
                r.u[i] = f2bf(sigmoid_safe(res[i] + bias2));
            unsigned short* outp = (unsigned short*)outv;
            if (e0 + EPW <= E) *(short8*)(outp + e0) = r.v;
            else for (int i = 0; i < EPW && e0 + i < E; ++i) outp[e0 + i] = r.u[i];
        } else {
            float* outp = (float*)outv;
            for (int i = 0; i < EPW && e0 + i < E; ++i)
                outp[e0 + i] = sigmoid_safe(res[i] + bias2);
        }
    }
}

// Zero-workspace fallback: one block per edge. flag==nullptr => assume MODE.
template <int MODE>
__global__ __launch_bounds__(256) void edge_fused_t(const void* __restrict__ hv,
                                                    const int* __restrict__ src,
                                                    const int* __restrict__ dst,
                                                    const void* __restrict__ W1v,
                                                    const void* __restrict__ b1v,
                                                    const void* __restrict__ W2v,
                                                    const void* __restrict__ b2v,
                                                    void* __restrict__ outv,
                                                    int E, const int* __restrict__ flag) {
    if (flag && flag[0] != MODE) return;
    __shared__ float he[512];
    __shared__ float wsum[4];
    const int e = blockIdx.x;
    if (e >= E) return;
    const int t = threadIdx.x;
    const int s = src[e];
    const int d = dst[e];

    if constexpr (MODE == 1) {
        he[t]       = bf2f(((const unsigned short*)hv)[(size_t)s * 256 + t]);
        he[256 + t] = bf2f(((const unsigned short*)hv)[(size_t)d * 256 + t]);
    } else {
        he[t]       = ((const float*)hv)[(size_t)s * 256 + t];
        he[256 + t] = ((const float*)hv)[(size_t)d * 256 + t];
    }
    __syncthreads();

    float acc;
    if constexpr (MODE == 1) acc = bf2f(((const unsigned short*)b1v)[t]);
    else                     acc = ((const float*)b1v)[t];

    #pragma unroll 8
    for (int k = 0; k < 512; ++k) {
        float w;
        if constexpr (MODE == 1) w = bf2f(((const unsigned short*)W1v)[(size_t)k * 256 + t]);
        else                     w = ((const float*)W1v)[(size_t)k * 256 + t];
        acc += he[k] * w;
    }

    float w2;
    if constexpr (MODE == 1) w2 = bf2f(((const unsigned short*)W2v)[t]);
    else                     w2 = ((const float*)W2v)[t];
    acc = fmaxf(acc, 0.f) * w2;

    #pragma unroll
    for (int off = 32; off > 0; off >>= 1)
        acc += __shfl_xor(acc, off);
    if ((t & 63) == 0) wsum[t >> 6] = acc;
    __syncthreads();

    if (t == 0) {
        float bias2;
        if constexpr (MODE == 1) bias2 = bf2f(((const unsigned short*)b2v)[0]);
        else                     bias2 = ((const float*)b2v)[0];
        float r = sigmoid_safe(wsum[0] + wsum[1] + wsum[2] + wsum[3] + bias2);
        if constexpr (MODE == 1) ((unsigned short*)outv)[e] = f2bf(r);
        else                     ((float*)outv)[e] = r;
    }
}

extern "C" void kernel_launch(void* const* d_in, const int* in_sizes, int n_in,
                              void* d_out, int out_size, void* d_ws, size_t ws_size,
                              hipStream_t stream) {
    const void* h  = d_in[0];
    const int* src = (const int*)d_in[1];
    const int* dst = (const int*)d_in[2];
    const void* W1 = d_in[3];
    const void* b1 = d_in[4];
    const void* W2 = d_in[5];
    const void* b2 = d_in[6];

    const int N = in_sizes[0] / D_FEAT;   // 100000
    const int E = in_sizes[1];            // 500000

    const size_t FLAG_BYTES = 256;
    const size_t wt_elems = (size_t)512 * D_FEAT;
    const size_t pq_elems = (size_t)N * 512;
    const size_t need = FLAG_BYTES + (wt_elems + pq_elems) * sizeof(unsigned short);

    int* flag = (int*)d_ws;
    unsigned short* Wt = (unsigned short*)((char*)d_ws + FLAG_BYTES);
    unsigned short* PQ = Wt + wt_elems;

    if (ws_size >= need) {
        probe_dtype<<<1, 256, 0, stream>>>((const unsigned short*)h, flag);

        build_wt_t<1><<<512, 256, 0, stream>>>(W1, Wt, flag);
        build_wt_t<0><<<512, 256, 0, stream>>>(W1, Wt, flag);

        int ggrid = (N + 63) / 64;
        gemm_pq_t<1><<<ggrid, 256, 0, stream>>>(h, Wt, PQ, N, flag);
        gemm_pq_t<0><<<ggrid, 256, 0, stream>>>(h, Wt, PQ, N, flag);

        int egrid = (E + 4 * EPW - 1) / (4 * EPW);
        edge_score_t<1><<<egrid, 256, 0, stream>>>(PQ, src, dst, b1, W2, b2, d_out, E, flag);
        edge_score_t<0><<<egrid, 256, 0, stream>>>(PQ, src, dst, b1, W2, b2, d_out, E, flag);
    } else if (ws_size >= FLAG_BYTES) {
        probe_dtype<<<1, 256, 0, stream>>>((const unsigned short*)h, flag);
        edge_fused_t<1><<<E, 256, 0, stream>>>(h, src, dst, W1, b1, W2, b2, d_out, E, flag);
        edge_fused_t<0><<<E, 256, 0, stream>>>(h, src, dst, W1, b1, W2, b2, d_out, E, flag);
    } else {
        edge_fused_t<1><<<E, 256, 0, stream>>>(h, src, dst, W1, b1, W2, b2, d_out, E, nullptr);
    }
}